// Round 13
// baseline (379.539 us; speedup 1.0000x reference)
//
#include <hip/hip_runtime.h>

#define CHUNK 400
#define LWIN 50
#define JUMP 8
#define NCH 128
#define BCH 128
#define HCH 512
#define NBLK 14
#define BUF 516
#define SHIFT 508
#define EPSV 1e-8f
#define NWG 136

// agent-coherent store/load: land at the coherence point (bypass per-XCD L2).
// Writers publish to L3; readers always see L3 -- no wbl2/inv ever needed,
// robust under buffer reuse and graph replays.
__device__ __forceinline__ void cstore(float* p, float v) {
    __hip_atomic_store(p, v, __ATOMIC_RELAXED, __HIP_MEMORY_SCOPE_AGENT);
}
__device__ __forceinline__ float cload(const float* p) {
    return __hip_atomic_load(p, __ATOMIC_RELAXED, __HIP_MEMORY_SCOPE_AGENT);
}

// point-to-point tile flags. fwait: lanes 0..cnt-1 poll one flag each, then
// block-barrier (orders subsequent data loads after flag observation).
__device__ __forceinline__ void fwait(unsigned* flp, int base, int cnt, int tid) {
    if (tid < cnt) {
        unsigned* p = flp + base + tid;
        while (__hip_atomic_load(p, __ATOMIC_RELAXED, __HIP_MEMORY_SCOPE_AGENT) == 0)
            __builtin_amdgcn_s_sleep(1);
    }
    __syncthreads();
}
// fset: __syncthreads drains each wave's vmcnt (reads returned, cstores acked
// at L3) before tid0 publishes -- this is what makes the WAR window sound.
__device__ __forceinline__ void fset(unsigned* flp, int idx, int tid) {
    __syncthreads();
    if (tid == 0)
        __hip_atomic_store(flp + idx, 1u, __ATOMIC_RELAXED, __HIP_MEMORY_SCOPE_AGENT);
}

// stage1: y1n[t0..t0+nf) = cLN(PReLU(w1 @ xs)); xs is LDS [4][128]
__device__ __forceinline__ void stage1_core(
    int tid, int lane, int wid, int t0, int nf,
    const float* __restrict__ w1b, float aPr,
    const float* __restrict__ gv, const float* __restrict__ bv,
    float* __restrict__ yout, float* redf, float* statsf, const float* xsv)
{
    float acc[4] = {0.f, 0.f, 0.f, 0.f};
    const float4* __restrict__ wr = (const float4*)(w1b + (size_t)tid * BCH);
    const float4* __restrict__ xv = (const float4*)xsv;
    #pragma unroll 4
    for (int c4 = 0; c4 < 32; ++c4) {
        float4 w = wr[c4];
        #pragma unroll
        for (int f = 0; f < 4; ++f) {
            float4 x = xv[f * 32 + c4];
            acc[f] += w.x * x.x + w.y * x.y + w.z * x.z + w.w * x.w;
        }
    }
    #pragma unroll
    for (int f = 0; f < 4; ++f) acc[f] = acc[f] >= 0.f ? acc[f] : aPr * acc[f];
    for (int f = 0; f < nf; ++f) {
        float s = acc[f], q = acc[f] * acc[f];
        #pragma unroll
        for (int o = 32; o; o >>= 1) { s += __shfl_xor(s, o); q += __shfl_xor(q, o); }
        if (lane == 0) { redf[(wid * 4 + f) * 2] = s; redf[(wid * 4 + f) * 2 + 1] = q; }
    }
    __syncthreads();
    if (tid < nf) {
        float s = 0.f, q = 0.f;
        #pragma unroll
        for (int w = 0; w < 8; ++w) { s += redf[(w * 4 + tid) * 2]; q += redf[(w * 4 + tid) * 2 + 1]; }
        float mean = s * (1.f / HCH);
        float var = q * (1.f / HCH) - mean * mean;
        statsf[tid * 2] = mean; statsf[tid * 2 + 1] = rsqrtf(var + EPSV);
    }
    __syncthreads();
    float gg = gv[tid], bb = bv[tid];
    for (int f = 0; f < nf; ++f)
        cstore(&yout[(t0 + f) * HCH + tid],
               gg * (acc[f] - statsf[f * 2]) * statsf[f * 2 + 1] + bb);
}

__global__ __launch_bounds__(512) void k_fused(
    const float* __restrict__ mixture, const float* __restrict__ inEnc,
    const float* __restrict__ inLn, const float* __restrict__ Wenc,
    const float* __restrict__ lng, const float* __restrict__ lnb,
    const float* __restrict__ Wbn, const float* __restrict__ w1,
    const float* __restrict__ p1, const float* __restrict__ g1,
    const float* __restrict__ b1, const float* __restrict__ dwc,
    const float* __restrict__ p2, const float* __restrict__ g2,
    const float* __restrict__ b2, const float* __restrict__ w2,
    const float* __restrict__ Wmask, const float* __restrict__ Wdec,
    float* __restrict__ est, float* __restrict__ outEnc, float* __restrict__ outLn,
    unsigned* __restrict__ fl, float* __restrict__ enc,
    float* __restrict__ xbuf, float* __restrict__ ybuf)
{
    __shared__ float xs[4 * BCH];
    __shared__ float ys[4 * 528];
    __shared__ float redf[8 * 4 * 2];
    __shared__ float statsf[4 * 2];

    const int wg = blockIdx.x;
    const int tid = threadIdx.x;
    const int lane = tid & 63, wid = tid >> 6;
    const int j = wg;
    const size_t xstr = (size_t)BUF * BCH;
    const size_t ystr = (size_t)BUF * HCH;

    // ===== phase 0: encoder+front (wg<8) | frame-major copies (wg 8..135) ====
    if (wg < 8) {
        int t = wg;
        float e = 0.f;
        if (tid < 128) {
            int c = tid;
            const float* w = Wenc + c * 100;
            const float* m = mixture + t * LWIN;
            #pragma unroll 10
            for (int l = 0; l < LWIN; ++l) e += m[l] * w[l] + m[CHUNK + l] * w[LWIN + l];
            e = fmaxf(e, 0.f);
            cstore(&enc[t * NCH + c], e);
            outEnc[c * BUF + SHIFT + t] = e;
            float s = e, q = e * e;
            #pragma unroll
            for (int o = 32; o; o >>= 1) { s += __shfl_xor(s, o); q += __shfl_xor(q, o); }
            if (lane == 0) { redf[(wid * 4) * 2] = s; redf[(wid * 4) * 2 + 1] = q; }
        }
        __syncthreads();
        if (tid < 128) {
            float S = redf[0] + redf[8], Q = redf[1] + redf[9];
            float mean = S * (1.f / NCH);
            float var = Q * (1.f / NCH) - mean * mean;
            float r = rsqrtf(var + EPSV);
            xs[tid] = lng[tid] * (e - mean) * r + lnb[tid];
        }
        __syncthreads();
        if (tid < 128) {
            float acc = 0.f;
            const float4* wr = (const float4*)(Wbn + tid * NCH);
            const float4* nv = (const float4*)xs;
            #pragma unroll 8
            for (int j4 = 0; j4 < 32; ++j4) {
                float4 w = wr[j4]; float4 x = nv[j4];
                acc += w.x * x.x + w.y * x.y + w.z * x.z + w.w * x.w;
            }
            outLn[tid * BUF + SHIFT + t] = acc;
            cstore(&xbuf[(SHIFT + t) * BCH + tid], acc);
        }
    } else {
        int ch = wg - 8;                           // 0..127
        for (int t = tid; t < SHIFT; t += 512)
            outEnc[ch * BUF + t] = inEnc[ch * BUF + t + JUMP];
        if (ch < 127) {                            // frames 4ch..4ch+3 of x0
            int f = tid >> 7, c = tid & 127;
            int t = 4 * ch + f;
            float v = inLn[c * BUF + t + JUMP];
            cstore(&xbuf[t * BCH + c], v);
            outLn[c * BUF + t] = v;
        }
    }
    fset(fl, 0 * NWG + wg, tid);

    // ===== phase 1: stage1 of block 0 ========================================
    if (4 * j < BUF) {
        int base, cnt;                 // x0 tile j producers (phase 0)
        if (j <= 126)      { base = 8 + j; cnt = 1; }
        else if (j == 127) { base = 0;     cnt = 4; }   // frames 508-511 <- wg 0-3
        else               { base = 4;     cnt = 4; }   // frames 512-515 <- wg 4-7
        fwait(fl, base, cnt, tid);
        int t0 = 4 * j;
        int nf = min(4, BUF - t0);
        for (int idx = tid; idx < nf * BCH; idx += 512) xs[idx] = cload(&xbuf[t0 * BCH + idx]);
        __syncthreads();
        stage1_core(tid, lane, wid, t0, nf, w1, p1[0], g1, b1, ybuf, redf, statsf, xs);
    }
    fset(fl, 1 * NWG + wg, tid);

    // ===== phases 2..15: stage2(i) fused with stage1(i+1) / mask+dec =========
    int T = BUF;
    for (int i = 0; i < NBLK; ++i) {
        const float* xin = xbuf + (size_t)(i & 1) * xstr;
        float* xout      = xbuf + (size_t)((i + 1) & 1) * xstr;
        const float* ycur = ybuf + (size_t)(i & 1) * ystr;
        float* ynext      = ybuf + (size_t)((i + 1) & 1) * ystr;
        int d = 1 << (i % 7);
        int Tout = T - 2 * d;
        int t0 = 4 * j;
        if (t0 < Tout) {
            // forward RAW window [j .. j+fwd] + backward WAR window [j-woff .. j]
            int jmaxe = (T - 1) >> 2;
            int jmax = min(j + ((3 + 2 * d) >> 2), jmaxe);
            int woff = (i >= 1 && i < NBLK - 1) ? ((3 + 2 * (1 << ((i - 1) % 7))) >> 2) : 0;
            int jlo = max(0, j - woff);
            fwait(fl + (1 + i) * NWG, jlo, jmax - jlo + 1, tid);
            if (i == NBLK - 1) fwait(fl, 4 * j, 4, tid);  // enc frames 4j..4j+3
            int nf = min(4, Tout - t0);
            // ---- depthwise conv + PReLU ----
            const float* dwb = dwc + (size_t)i * HCH * 3;
            float d0 = dwb[tid * 3], d1 = dwb[tid * 3 + 1], d2 = dwb[tid * 3 + 2];
            float a2 = p2[i];
            float y[4];
            for (int f = 0; f < nf; ++f) {
                int t = t0 + f;
                float v = d0 * cload(&ycur[t * HCH + tid])
                        + d1 * cload(&ycur[(t + d) * HCH + tid])
                        + d2 * cload(&ycur[(t + 2 * d) * HCH + tid]);
                y[f] = v >= 0.f ? v : a2 * v;
            }
            // ---- cLN over H ----
            for (int f = 0; f < nf; ++f) {
                float s = y[f], q = y[f] * y[f];
                #pragma unroll
                for (int o = 32; o; o >>= 1) { s += __shfl_xor(s, o); q += __shfl_xor(q, o); }
                if (lane == 0) { redf[(wid * 4 + f) * 2] = s; redf[(wid * 4 + f) * 2 + 1] = q; }
            }
            __syncthreads();
            if (tid < nf) {
                float s = 0.f, q = 0.f;
                #pragma unroll
                for (int w = 0; w < 8; ++w) { s += redf[(w * 4 + tid) * 2]; q += redf[(w * 4 + tid) * 2 + 1]; }
                float mean = s * (1.f / HCH);
                float var = q * (1.f / HCH) - mean * mean;
                statsf[tid * 2] = mean; statsf[tid * 2 + 1] = rsqrtf(var + EPSV);
            }
            __syncthreads();
            {
                float gg = g2[i * HCH + tid], bb = b2[i * HCH + tid];
                int pidx = (tid >> 7) * 132 + (tid & 127);
                for (int f = 0; f < nf; ++f)
                    ys[f * 528 + pidx] = gg * (y[f] - statsf[f * 2]) * statsf[f * 2 + 1] + bb;
            }
            __syncthreads();
            // ---- w2 GEMM (K split by 4) + residual ----
            int c = tid >> 2, p = tid & 3;
            float acc[4] = {0.f, 0.f, 0.f, 0.f};
            const float4* wr = (const float4*)(w2 + (size_t)i * BCH * HCH + c * HCH + p * 128);
            const float* yb = ys + p * 132;
            #pragma unroll 4
            for (int j4 = 0; j4 < 32; ++j4) {
                float4 w = wr[j4];
                #pragma unroll
                for (int f = 0; f < 4; ++f) {
                    float4 x = *(const float4*)&yb[f * 528 + j4 * 4];
                    acc[f] += w.x * x.x + w.y * x.y + w.z * x.z + w.w * x.w;
                }
            }
            for (int f = 0; f < nf; ++f) {
                acc[f] += __shfl_xor(acc[f], 1);
                acc[f] += __shfl_xor(acc[f], 2);
            }
            if (p == 0) {
                for (int f = 0; f < nf; ++f) {
                    int t = t0 + f;
                    float xv = cload(&xin[(t + 2 * d) * BCH + c]) + acc[f];
                    cstore(&xout[t * BCH + c], xv);
                    xs[f * BCH + c] = xv;
                }
            }
            __syncthreads();
            // ---- fused next stage1 (or mask+decoder on the last block) ----
            if (i < NBLK - 1) {
                stage1_core(tid, lane, wid, t0, nf,
                            w1 + (size_t)(i + 1) * HCH * BCH, p1[i + 1],
                            g1 + (i + 1) * HCH, b1 + (i + 1) * HCH, ynext, redf, statsf, xs);
            } else {
                int cc = tid & 127, f = tid >> 7;
                float m = 0.f;
                const float4* wm = (const float4*)(Wmask + cc * BCH);
                const float4* xv = (const float4*)(xs + f * BCH);
                #pragma unroll 8
                for (int j4 = 0; j4 < 32; ++j4) {
                    float4 w = wm[j4]; float4 x = xv[j4];
                    m += w.x * x.x + w.y * x.y + w.z * x.z + w.w * x.w;
                }
                m = fmaxf(m, 0.f);
                ys[f * BCH + cc] = m * cload(&enc[(t0 + f) * NCH + cc]);
                __syncthreads();
                if (tid < 4 * LWIN) {
                    int ff = tid / LWIN, l = tid % LWIN;
                    float e = 0.f;
                    const float4* wd = (const float4*)(Wdec + l * NCH);
                    const float4* sv = (const float4*)(ys + ff * BCH);
                    #pragma unroll 8
                    for (int j4 = 0; j4 < 32; ++j4) {
                        float4 w = wd[j4]; float4 x = sv[j4];
                        e += w.x * x.x + w.y * x.y + w.z * x.z + w.w * x.w;
                    }
                    est[(t0 + ff) * LWIN + l] = e;
                }
            }
        }
        fset(fl, (2 + i) * NWG + wg, tid);
        T = Tout;
    }
}

extern "C" void kernel_launch(void* const* d_in, const int* in_sizes, int n_in,
                              void* d_out, int out_size, void* d_ws, size_t ws_size,
                              hipStream_t stream) {
    const float* mixture = (const float*)d_in[0];
    const float* inEnc   = (const float*)d_in[1];
    const float* inLn    = (const float*)d_in[2];
    const float* Wenc    = (const float*)d_in[3];
    const float* lng     = (const float*)d_in[4];
    const float* lnb     = (const float*)d_in[5];
    const float* Wbn     = (const float*)d_in[6];
    const float* w1      = (const float*)d_in[7];
    const float* p1      = (const float*)d_in[8];
    const float* g1      = (const float*)d_in[9];
    const float* b1      = (const float*)d_in[10];
    const float* dwc     = (const float*)d_in[11];
    const float* p2      = (const float*)d_in[12];
    const float* g2      = (const float*)d_in[13];
    const float* b2      = (const float*)d_in[14];
    const float* w2      = (const float*)d_in[15];
    const float* Wmask   = (const float*)d_in[16];
    const float* Wdec    = (const float*)d_in[17];

    float* est    = (float*)d_out;
    float* outEnc = est + CHUNK;
    float* outLn  = outEnc + NCH * BUF;

    unsigned* fl = (unsigned*)d_ws;           // 16 x 136 flags = 8704 B
    float* enc  = (float*)d_ws + 2304;        // 9216 B offset
    float* xbuf = enc + 1024;                 // 2 x 66048
    float* ybuf = xbuf + 2 * (size_t)BUF * BCH;  // 2 x 264192  (total ~2.7 MB)

    hipMemsetAsync(d_ws, 0, 9216, stream);

    void* args[] = { &mixture, &inEnc, &inLn, &Wenc, &lng, &lnb, &Wbn, &w1, &p1,
                     &g1, &b1, &dwc, &p2, &g2, &b2, &w2, &Wmask, &Wdec,
                     &est, &outEnc, &outLn, &fl, &enc, &xbuf, &ybuf };
    hipLaunchCooperativeKernel((const void*)k_fused, dim3(NWG), dim3(512),
                               (void**)args, 0, stream);
}

// Round 15
// 332.359 us; speedup vs baseline: 1.1420x; 1.1420x over previous
//
#include <hip/hip_runtime.h>

#define CHUNK 400
#define LWIN 50
#define JUMP 8
#define NCH 128
#define BCH 128
#define HCH 512
#define NBLK 14
#define BUF 516
#define SHIFT 508
#define EPSV 1e-8f
#define NWG 136

typedef float f4v __attribute__((ext_vector_type(4)));

// ---- coherent (L2-bypassing, agent-visible) 16B ops via sc0 sc1 ----
__device__ __forceinline__ void cstore4(float* p, float4 v) {
    f4v t = {v.x, v.y, v.z, v.w};
    asm volatile("global_store_dwordx4 %0, %1, off sc0 sc1"
                 :: "v"(p), "v"(t) : "memory");
}
__device__ __forceinline__ float4 cload4(const float* p) {
    f4v t;
    asm volatile("global_load_dwordx4 %0, %1, off sc0 sc1\n\ts_waitcnt vmcnt(0)"
                 : "=v"(t) : "v"(p) : "memory");
    return make_float4(t.x, t.y, t.z, t.w);
}
__device__ __forceinline__ void cload4x3(float4& a, float4& b, float4& c,
        const float* pa, const float* pb, const float* pc) {
    f4v ta, tb, tc;
    asm volatile("global_load_dwordx4 %0, %3, off sc0 sc1\n\t"
                 "global_load_dwordx4 %1, %4, off sc0 sc1\n\t"
                 "global_load_dwordx4 %2, %5, off sc0 sc1\n\t"
                 "s_waitcnt vmcnt(0)"
                 : "=&v"(ta), "=&v"(tb), "=&v"(tc)
                 : "v"(pa), "v"(pb), "v"(pc) : "memory");
    a = make_float4(ta.x, ta.y, ta.z, ta.w);
    b = make_float4(tb.x, tb.y, tb.z, tb.w);
    c = make_float4(tc.x, tc.y, tc.z, tc.w);
}
__device__ __forceinline__ void cstore(float* p, float v) {
    __hip_atomic_store(p, v, __ATOMIC_RELAXED, __HIP_MEMORY_SCOPE_AGENT);
}
__device__ __forceinline__ float cload(const float* p) {
    return __hip_atomic_load(p, __ATOMIC_RELAXED, __HIP_MEMORY_SCOPE_AGENT);
}

// ---- p2p tile flags (proven R13) ----
__device__ __forceinline__ void fwait(unsigned* flp, int base, int cnt, int tid) {
    if (tid < cnt) {
        unsigned* p = flp + base + tid;
        while (__hip_atomic_load(p, __ATOMIC_RELAXED, __HIP_MEMORY_SCOPE_AGENT) == 0)
            __builtin_amdgcn_s_sleep(1);
    }
    __syncthreads();
}
__device__ __forceinline__ void fset(unsigned* flp, int idx, int tid) {
    __syncthreads();                 // drains vmcnt: all cstore4 acked at L3
    if (tid == 0)
        __hip_atomic_store(flp + idx, 1u, __ATOMIC_RELAXED, __HIP_MEMORY_SCOPE_AGENT);
}

// stage1: cLN(PReLU(w1 @ xs)) -> float4 coherent stores via LDS transpose
__device__ __forceinline__ void stage1_core(
    int tid, int lane, int wid, int t0, int nf,
    const float* __restrict__ w1b, float aPr,
    const float* __restrict__ gv, const float* __restrict__ bv,
    float* __restrict__ yout, float* redf, float* statsf,
    const float* xsv, float* ysT)
{
    float acc[4] = {0.f, 0.f, 0.f, 0.f};
    const float4* __restrict__ wr = (const float4*)(w1b + (size_t)tid * BCH);
    const float4* __restrict__ xv = (const float4*)xsv;
    #pragma unroll 4
    for (int c4 = 0; c4 < 32; ++c4) {
        float4 w = wr[c4];
        #pragma unroll
        for (int f = 0; f < 4; ++f) {
            float4 x = xv[f * 32 + c4];
            acc[f] += w.x * x.x + w.y * x.y + w.z * x.z + w.w * x.w;
        }
    }
    #pragma unroll
    for (int f = 0; f < 4; ++f) acc[f] = acc[f] >= 0.f ? acc[f] : aPr * acc[f];
    for (int f = 0; f < nf; ++f) {
        float s = acc[f], q = acc[f] * acc[f];
        #pragma unroll
        for (int o = 32; o; o >>= 1) { s += __shfl_xor(s, o); q += __shfl_xor(q, o); }
        if (lane == 0) { redf[(wid * 4 + f) * 2] = s; redf[(wid * 4 + f) * 2 + 1] = q; }
    }
    __syncthreads();
    if (tid < nf) {
        float s = 0.f, q = 0.f;
        #pragma unroll
        for (int w = 0; w < 8; ++w) { s += redf[(w * 4 + tid) * 2]; q += redf[(w * 4 + tid) * 2 + 1]; }
        float mean = s * (1.f / HCH);
        float var = q * (1.f / HCH) - mean * mean;
        statsf[tid * 2] = mean; statsf[tid * 2 + 1] = rsqrtf(var + EPSV);
    }
    __syncthreads();
    float gg = gv[tid], bb = bv[tid];
    for (int f = 0; f < nf; ++f)
        ysT[f * HCH + tid] = gg * (acc[f] - statsf[f * 2]) * statsf[f * 2 + 1] + bb;
    __syncthreads();
    int f2 = tid >> 7, h4 = tid & 127;
    if (f2 < nf)
        cstore4(&yout[(t0 + f2) * HCH + 4 * h4], *(float4*)&ysT[f2 * HCH + 4 * h4]);
}

__global__ __launch_bounds__(512) void k_fused(
    const float* __restrict__ mixture, const float* __restrict__ inEnc,
    const float* __restrict__ inLn, const float* __restrict__ Wenc,
    const float* __restrict__ lng, const float* __restrict__ lnb,
    const float* __restrict__ Wbn, const float* __restrict__ w1,
    const float* __restrict__ p1, const float* __restrict__ g1,
    const float* __restrict__ b1, const float* __restrict__ dwc,
    const float* __restrict__ p2, const float* __restrict__ g2,
    const float* __restrict__ b2, const float* __restrict__ w2,
    const float* __restrict__ Wmask, const float* __restrict__ Wdec,
    float* __restrict__ est, float* __restrict__ outEnc, float* __restrict__ outLn,
    unsigned* __restrict__ fl, float* __restrict__ enc,
    float* __restrict__ xbuf, float* __restrict__ ybuf)
{
    __shared__ float xs[4 * BCH];
    __shared__ float ys[4 * 528];        // GEMM input (padded) / stage1 transpose / sw
    __shared__ float redf[8 * 4 * 2];
    __shared__ float statsf[4 * 2];

    const int wg = blockIdx.x;
    const int tid = threadIdx.x;
    const int lane = tid & 63, wid = tid >> 6;
    const int j = wg;
    const size_t xstr = (size_t)BUF * BCH;
    const size_t ystr = (size_t)BUF * HCH;

    // ===== phase 0: encoder+front (wg<8) | copies (wg 8..135) ================
    if (wg < 8) {
        int t = wg;
        float e = 0.f;
        if (tid < 128) {
            int c = tid;
            const float* w = Wenc + c * 100;
            const float* m = mixture + t * LWIN;
            #pragma unroll 10
            for (int l = 0; l < LWIN; ++l) e += m[l] * w[l] + m[CHUNK + l] * w[LWIN + l];
            e = fmaxf(e, 0.f);
            cstore(&enc[t * NCH + c], e);
            outEnc[c * BUF + SHIFT + t] = e;
            float s = e, q = e * e;
            #pragma unroll
            for (int o = 32; o; o >>= 1) { s += __shfl_xor(s, o); q += __shfl_xor(q, o); }
            if (lane == 0) { redf[(wid * 4) * 2] = s; redf[(wid * 4) * 2 + 1] = q; }
        }
        __syncthreads();
        if (tid < 128) {
            float S = redf[0] + redf[8], Q = redf[1] + redf[9];
            float mean = S * (1.f / NCH);
            float var = Q * (1.f / NCH) - mean * mean;
            float r = rsqrtf(var + EPSV);
            xs[tid] = lng[tid] * (e - mean) * r + lnb[tid];
        }
        __syncthreads();
        if (tid < 128) {
            float acc = 0.f;
            const float4* wr = (const float4*)(Wbn + tid * NCH);
            const float4* nv = (const float4*)xs;
            #pragma unroll 8
            for (int j4 = 0; j4 < 32; ++j4) {
                float4 w = wr[j4]; float4 x = nv[j4];
                acc += w.x * x.x + w.y * x.y + w.z * x.z + w.w * x.w;
            }
            outLn[tid * BUF + SHIFT + t] = acc;
            ys[tid] = acc;                       // stage to LDS for float4 store
        }
        __syncthreads();
        if (tid < 32)
            cstore4(&xbuf[(SHIFT + t) * BCH + 4 * tid], *(float4*)&ys[4 * tid]);
    } else {
        int ch = wg - 8;                           // 0..127
        for (int t = tid; t < SHIFT; t += 512)
            outEnc[ch * BUF + t] = inEnc[ch * BUF + t + JUMP];
        if (ch < 127) {                            // frames 4ch..4ch+3 of x0
            int f = tid >> 7, c = tid & 127;
            int t = 4 * ch + f;
            float v = inLn[c * BUF + t + JUMP];
            outLn[c * BUF + t] = v;
            ys[f * BCH + c] = v;
        }
        __syncthreads();
        if (ch < 127 && tid < 128) {               // float4 coherent writes
            int f = tid >> 5, c4 = tid & 31;
            cstore4(&xbuf[(4 * ch + f) * BCH + 4 * c4], *(float4*)&ys[f * BCH + 4 * c4]);
        }
    }
    fset(fl, 0 * NWG + wg, tid);

    // ===== phase 1: stage1 of block 0 ========================================
    if (4 * j < BUF) {
        int base, cnt;
        if (j <= 126)      { base = 8 + j; cnt = 1; }
        else if (j == 127) { base = 0;     cnt = 4; }
        else               { base = 4;     cnt = 4; }
        fwait(fl, base, cnt, tid);
        int t0 = 4 * j;
        int nf = min(4, BUF - t0);                 // always 4 (516 % 4 == 0)
        if (tid < nf * 32) {
            float4 v = cload4(&xbuf[t0 * BCH + 4 * tid]);
            *(float4*)&xs[4 * tid] = v;
        }
        __syncthreads();
        stage1_core(tid, lane, wid, t0, nf, w1, p1[0], g1, b1, ybuf, redf, statsf, xs, ys);
    }
    fset(fl, 1 * NWG + wg, tid);

    // ===== phases 2..15: stage2(i) fused with stage1(i+1) / mask+dec =========
    int T = BUF;
    for (int i = 0; i < NBLK; ++i) {
        const float* xin = xbuf + (size_t)(i & 1) * xstr;
        float* xout      = xbuf + (size_t)((i + 1) & 1) * xstr;
        const float* ycur = ybuf + (size_t)(i & 1) * ystr;
        float* ynext      = ybuf + (size_t)((i + 1) & 1) * ystr;
        int d = 1 << (i % 7);
        int Tout = T - 2 * d;
        int t0 = 4 * j;
        if (t0 < Tout) {
            int jmaxe = (T - 1) >> 2;
            int jmax = min(j + ((3 + 2 * d) >> 2), jmaxe);
            int woff = (i >= 1 && i < NBLK - 1) ? ((3 + 2 * (1 << ((i - 1) % 7))) >> 2) : 0;
            int jlo = max(0, j - woff);
            fwait(fl + (1 + i) * NWG, jlo, jmax - jlo + 1, tid);
            if (i == NBLK - 1) fwait(fl, 4 * j, 4, tid);
            int nf = min(4, Tout - t0);
            // ---- depthwise conv + PReLU: thread=(frame f, h4), float4-wide ----
            const int f = tid >> 7, h4 = tid & 127;
            float4 yv; yv.x = yv.y = yv.z = yv.w = 0.f;
            if (f < nf) {
                float4 ya, yb2, yc;
                cload4x3(ya, yb2, yc,
                         &ycur[(t0 + f) * HCH + 4 * h4],
                         &ycur[(t0 + f + d) * HCH + 4 * h4],
                         &ycur[(t0 + f + 2 * d) * HCH + 4 * h4]);
                const float* dwb = dwc + (size_t)i * HCH * 3 + 12 * h4;
                float4 w0 = *(const float4*)(dwb);
                float4 w1v = *(const float4*)(dwb + 4);
                float4 w2v = *(const float4*)(dwb + 8);
                float a2 = p2[i];
                yv.x = w0.x * ya.x + w0.y * yb2.x + w0.z * yc.x;
                yv.y = w0.w * ya.y + w1v.x * yb2.y + w1v.y * yc.y;
                yv.z = w1v.z * ya.z + w1v.w * yb2.z + w2v.x * yc.z;
                yv.w = w2v.y * ya.w + w2v.z * yb2.w + w2v.w * yc.w;
                yv.x = yv.x >= 0.f ? yv.x : a2 * yv.x;
                yv.y = yv.y >= 0.f ? yv.y : a2 * yv.y;
                yv.z = yv.z >= 0.f ? yv.z : a2 * yv.z;
                yv.w = yv.w >= 0.f ? yv.w : a2 * yv.w;
            }
            // ---- cLN over H: frame f = waves 2f,2f+1 ----
            {
                float s = yv.x + yv.y + yv.z + yv.w;
                float q = yv.x * yv.x + yv.y * yv.y + yv.z * yv.z + yv.w * yv.w;
                #pragma unroll
                for (int o = 32; o; o >>= 1) { s += __shfl_xor(s, o); q += __shfl_xor(q, o); }
                if (lane == 0 && f < nf) { redf[wid * 2] = s; redf[wid * 2 + 1] = q; }
            }
            __syncthreads();
            if (tid < nf) {
                float s = redf[4 * tid] + redf[4 * tid + 2];
                float q = redf[4 * tid + 1] + redf[4 * tid + 3];
                float mean = s * (1.f / HCH);
                float var = q * (1.f / HCH) - mean * mean;
                statsf[tid * 2] = mean; statsf[tid * 2 + 1] = rsqrtf(var + EPSV);
            }
            __syncthreads();
            if (f < nf) {
                float mean = statsf[f * 2], rstd = statsf[f * 2 + 1];
                float4 gv = *(const float4*)&g2[i * HCH + 4 * h4];
                float4 bv = *(const float4*)&b2[i * HCH + 4 * h4];
                float4 nv;
                nv.x = gv.x * (yv.x - mean) * rstd + bv.x;
                nv.y = gv.y * (yv.y - mean) * rstd + bv.y;
                nv.z = gv.z * (yv.z - mean) * rstd + bv.z;
                nv.w = gv.w * (yv.w - mean) * rstd + bv.w;
                *(float4*)&ys[f * 528 + (h4 >> 5) * 132 + (h4 & 31) * 4] = nv;
            }
            __syncthreads();
            // ---- w2 GEMM (K split by 4) ----
            int c = tid >> 2, p = tid & 3;
            float acc[4] = {0.f, 0.f, 0.f, 0.f};
            const float4* wr = (const float4*)(w2 + (size_t)i * BCH * HCH + c * HCH + p * 128);
            const float* yb = ys + p * 132;
            #pragma unroll 4
            for (int j4 = 0; j4 < 32; ++j4) {
                float4 w = wr[j4];
                #pragma unroll
                for (int ff = 0; ff < 4; ++ff) {
                    float4 x = *(const float4*)&yb[ff * 528 + j4 * 4];
                    acc[ff] += w.x * x.x + w.y * x.y + w.z * x.z + w.w * x.w;
                }
            }
            for (int ff = 0; ff < nf; ++ff) {
                acc[ff] += __shfl_xor(acc[ff], 1);
                acc[ff] += __shfl_xor(acc[ff], 2);
            }
            if (p == 0)
                for (int ff = 0; ff < nf; ++ff) xs[ff * BCH + c] = acc[ff];
            __syncthreads();
            // ---- residual add + x store (float4) ----
            if (tid < 128) {
                int f2 = tid >> 5, c4 = tid & 31;
                if (f2 < nf) {
                    float4 xr = cload4(&xin[(t0 + f2 + 2 * d) * BCH + 4 * c4]);
                    float4 xa = *(float4*)&xs[f2 * BCH + 4 * c4];
                    xa.x += xr.x; xa.y += xr.y; xa.z += xr.z; xa.w += xr.w;
                    *(float4*)&xs[f2 * BCH + 4 * c4] = xa;
                    cstore4(&xout[(t0 + f2) * BCH + 4 * c4], xa);
                }
            }
            __syncthreads();
            // ---- fused next stage1 (or mask+decoder on the last block) ----
            if (i < NBLK - 1) {
                stage1_core(tid, lane, wid, t0, nf,
                            w1 + (size_t)(i + 1) * HCH * BCH, p1[i + 1],
                            g1 + (i + 1) * HCH, b1 + (i + 1) * HCH, ynext,
                            redf, statsf, xs, ys);
            } else {
                int cc = tid & 127, f3 = tid >> 7;
                float m = 0.f;
                const float4* wm = (const float4*)(Wmask + cc * BCH);
                const float4* xv = (const float4*)(xs + f3 * BCH);
                #pragma unroll 8
                for (int j4 = 0; j4 < 32; ++j4) {
                    float4 w = wm[j4]; float4 x = xv[j4];
                    m += w.x * x.x + w.y * x.y + w.z * x.z + w.w * x.w;
                }
                m = fmaxf(m, 0.f);
                ys[f3 * BCH + cc] = m * cload(&enc[(t0 + f3) * NCH + cc]);
                __syncthreads();
                if (tid < 4 * LWIN) {
                    int ff = tid / LWIN, l = tid % LWIN;
                    float e = 0.f;
                    const float4* wd = (const float4*)(Wdec + l * NCH);
                    const float4* sv = (const float4*)(ys + ff * BCH);
                    #pragma unroll 8
                    for (int j4 = 0; j4 < 32; ++j4) {
                        float4 w = wd[j4]; float4 x = sv[j4];
                        e += w.x * x.x + w.y * x.y + w.z * x.z + w.w * x.w;
                    }
                    est[(t0 + ff) * LWIN + l] = e;
                }
            }
        }
        fset(fl, (2 + i) * NWG + wg, tid);
        T = Tout;
    }
}

extern "C" void kernel_launch(void* const* d_in, const int* in_sizes, int n_in,
                              void* d_out, int out_size, void* d_ws, size_t ws_size,
                              hipStream_t stream) {
    const float* mixture = (const float*)d_in[0];
    const float* inEnc   = (const float*)d_in[1];
    const float* inLn    = (const float*)d_in[2];
    const float* Wenc    = (const float*)d_in[3];
    const float* lng     = (const float*)d_in[4];
    const float* lnb     = (const float*)d_in[5];
    const float* Wbn     = (const float*)d_in[6];
    const float* w1      = (const float*)d_in[7];
    const float* p1      = (const float*)d_in[8];
    const float* g1      = (const float*)d_in[9];
    const float* b1      = (const float*)d_in[10];
    const float* dwc     = (const float*)d_in[11];
    const float* p2      = (const float*)d_in[12];
    const float* g2      = (const float*)d_in[13];
    const float* b2      = (const float*)d_in[14];
    const float* w2      = (const float*)d_in[15];
    const float* Wmask   = (const float*)d_in[16];
    const float* Wdec    = (const float*)d_in[17];

    float* est    = (float*)d_out;
    float* outEnc = est + CHUNK;
    float* outLn  = outEnc + NCH * BUF;

    unsigned* fl = (unsigned*)d_ws;              // 16 x 136 flags = 8704 B
    float* enc  = (float*)d_ws + 2304;           // 9216 B offset
    float* xbuf = enc + 1024;                    // 2 x 66048 (16B-aligned)
    float* ybuf = xbuf + 2 * (size_t)BUF * BCH;  // 2 x 264192

    (void)hipMemsetAsync(d_ws, 0, 9216, stream);

    void* args[] = { &mixture, &inEnc, &inLn, &Wenc, &lng, &lnb, &Wbn, &w1, &p1,
                     &g1, &b1, &dwc, &p2, &g2, &b2, &w2, &Wmask, &Wdec,
                     &est, &outEnc, &outLn, &fl, &enc, &xbuf, &ybuf };
    (void)hipLaunchCooperativeKernel((const void*)k_fused, dim3(NWG), dim3(512),
                                     (void**)args, 0, stream);
}